// Round 8
// baseline (338.698 us; speedup 1.0000x reference)
//
#include <hip/hip_runtime.h>
#include <hip/hip_bf16.h>
#include <stdint.h>

typedef __bf16 bf16x8 __attribute__((ext_vector_type(8)));
typedef float  f32x4  __attribute__((ext_vector_type(4)));

#define M_NODES 100000
#define K_IN    256
#define N_OUT   128
#define N_EDGE  1600000

// ---------------------------------------------------------------------------
// Prep: Bt[n][k] = bf16( w[k][n] ) — 64 KB transposed weight table so GEMM
// B-fragments become single 16B loads (k contiguous per lane). Runs once per
// launch; w is 128 KB so cost is trivial.
// ---------------------------------------------------------------------------
__global__ __launch_bounds__(256) void prep_bt(const float* __restrict__ w,
                                               __hip_bfloat16* __restrict__ bt) {
    const int col = blockIdx.x;              // 0..127
    const int k   = threadIdx.x;             // 0..255
    bt[(size_t)col * K_IN + k] = __float2bfloat16(w[(size_t)k * N_OUT + col]);
}

// ---------------------------------------------------------------------------
// Stage 1 v2: h[M,N] = in[M,K] @ w[K,N], MFMA 16x16x32 bf16, fp32 accum.
// Wave = 16 rows x 128 cols (8 n-tiles): A rows loaded exactly once chip-wide
// (no cross-wave redundancy), B frags = 1 dwordx4 each from the 64 KB Bt
// table (L1/L2-resident). No LDS, no barriers.
// Block 256 = 4 waves = 64 rows. fp32 h nontemporal + bf16 mirror for stage 2.
// ---------------------------------------------------------------------------
__global__ __launch_bounds__(256) void gemm_h_mfma2(
    const float* __restrict__ in,            // [M,K] fp32
    const __hip_bfloat16* __restrict__ bt,   // [N,K] bf16 (transposed w)
    float* __restrict__ h,                   // [M,N] fp32 (d_out)
    __hip_bfloat16* __restrict__ hmir)       // [M,N] bf16 mirror (or null)
{
    const int lane = threadIdx.x & 63;
    const int wave = threadIdx.x >> 6;       // 0..3
    const int lr   = lane & 15;              // m (A) / n (B,C) within tile
    const int q    = lane >> 4;              // quad 0..3
    const int m0   = blockIdx.x * 64 + wave * 16;
    const int row  = m0 + lr;
    const __bf16* btb = (const __bf16*)bt;

    f32x4 acc[8];
    #pragma unroll
    for (int nt = 0; nt < 8; ++nt) acc[nt] = f32x4{0.f, 0.f, 0.f, 0.f};

    for (int kk = 0; kk < K_IN; kk += 32) {
        const int ka = kk + q * 8;           // lane's 8 contiguous k

        bf16x8 afrag;                        // A[m=lr][k=ka..ka+7]
        if (row < M_NODES) {
            const float* ap = in + (size_t)row * K_IN + ka;
            const f32x4 a0 = *(const f32x4*)ap;
            const f32x4 a1 = *(const f32x4*)(ap + 4);
            #pragma unroll
            for (int j = 0; j < 4; ++j) {
                afrag[j]     = (__bf16)a0[j];
                afrag[4 + j] = (__bf16)a1[j];
            }
        } else {
            #pragma unroll
            for (int j = 0; j < 8; ++j) afrag[j] = (__bf16)0.f;
        }

        bf16x8 bfrag[8];                     // B[k=ka+j][n=nt*16+lr] = Bt[n][k..]
        #pragma unroll
        for (int nt = 0; nt < 8; ++nt)
            bfrag[nt] = *(const bf16x8*)(btb + (size_t)(nt * 16 + lr) * K_IN + ka);

        #pragma unroll
        for (int nt = 0; nt < 8; ++nt)
            acc[nt] = __builtin_amdgcn_mfma_f32_16x16x32_bf16(
                afrag, bfrag[nt], acc[nt], 0, 0, 0);
    }

    // C/D: col = lane&15, row = (lane>>4)*4 + reg
    const int rb = m0 + q * 4;
    if (rb < M_NODES) {                      // M%4==0: rb<M => rb+3<M
        #pragma unroll
        for (int nt = 0; nt < 8; ++nt) {
            const int col = nt * 16 + lr;
            #pragma unroll
            for (int r = 0; r < 4; ++r) {
                const float v = acc[nt][r];
                __builtin_nontemporal_store(v, h + (size_t)(rb + r) * N_OUT + col);
                if (hmir)
                    hmir[(size_t)(rb + r) * N_OUT + col] = __float2bfloat16(v);
            }
        }
    }
}

// ---------------------------------------------------------------------------
// Fallback stage 1 (no workspace): scalar-B MFMA GEMM (R7 version).
// ---------------------------------------------------------------------------
__global__ __launch_bounds__(256) void gemm_h_mfma(
    const float* __restrict__ in, const float* __restrict__ w,
    float* __restrict__ h, __hip_bfloat16* __restrict__ hmir)
{
    const int lane = threadIdx.x & 63;
    const int wave = threadIdx.x >> 6;
    const int m0   = blockIdx.x * 64;
    const int nb   = wave * 32;
    const int lr = lane & 15;
    const int q  = lane >> 4;

    f32x4 acc[4][2];
    #pragma unroll
    for (int mt = 0; mt < 4; ++mt)
        #pragma unroll
        for (int nt = 0; nt < 2; ++nt)
            acc[mt][nt] = f32x4{0.f, 0.f, 0.f, 0.f};

    for (int kk = 0; kk < K_IN; kk += 32) {
        const int ka = kk + q * 8;
        bf16x8 afrag[4];
        #pragma unroll
        for (int mt = 0; mt < 4; ++mt) {
            const int row = m0 + mt * 16 + lr;
            if (row < M_NODES) {
                const float* ap = in + (size_t)row * K_IN + ka;
                const f32x4 a0 = *(const f32x4*)ap;
                const f32x4 a1 = *(const f32x4*)(ap + 4);
                #pragma unroll
                for (int j = 0; j < 4; ++j) {
                    afrag[mt][j] = (__bf16)a0[j];
                    afrag[mt][4 + j] = (__bf16)a1[j];
                }
            } else {
                #pragma unroll
                for (int j = 0; j < 8; ++j) afrag[mt][j] = (__bf16)0.f;
            }
        }
        bf16x8 bfrag[2];
        #pragma unroll
        for (int nt = 0; nt < 2; ++nt) {
            const int col = nb + nt * 16 + lr;
            #pragma unroll
            for (int j = 0; j < 8; ++j)
                bfrag[nt][j] = (__bf16)w[(size_t)(ka + j) * N_OUT + col];
        }
        #pragma unroll
        for (int mt = 0; mt < 4; ++mt)
            #pragma unroll
            for (int nt = 0; nt < 2; ++nt)
                acc[mt][nt] = __builtin_amdgcn_mfma_f32_16x16x32_bf16(
                    afrag[mt], bfrag[nt], acc[mt][nt], 0, 0, 0);
    }
    #pragma unroll
    for (int mt = 0; mt < 4; ++mt) {
        const int rb = m0 + mt * 16 + q * 4;
        if (rb >= M_NODES) continue;
        #pragma unroll
        for (int nt = 0; nt < 2; ++nt) {
            const int col = nb + nt * 16 + lr;
            #pragma unroll
            for (int r = 0; r < 4; ++r) {
                const float v = acc[mt][nt][r];
                __builtin_nontemporal_store(v, h + (size_t)(rb + r) * N_OUT + col);
                if (hmir)
                    hmir[(size_t)(rb + r) * N_OUT + col] = __float2bfloat16(v);
            }
        }
    }
}

// int64 edge indices < 1e5: every high word is 0. int32: odd words random.
__device__ inline int detect_i64(const uint32_t* p) {
    return __popcll(__ballot(p[2 * (threadIdx.x & 63) + 1] == 0u)) >= 60;
}

// ---------------------------------------------------------------------------
// Stage 2: edge_weight[e] = relu( sum_k |h[src][k] - h[dst][k]| * a[k] ).
// 16 lanes per edge; lane covers 8 contiguous channels (16B bf16 loads).
// ---------------------------------------------------------------------------
__global__ __launch_bounds__(256) void edge_kernel_bf16(
    const __hip_bfloat16* __restrict__ hm,
    const uint32_t* __restrict__ edge_raw,
    const float* __restrict__ a,
    float* __restrict__ ew,
    int E)
{
    const int e64 = detect_i64(edge_raw);
    const int s = threadIdx.x & 15;
    const int e = (int)((blockIdx.x * 256 + threadIdx.x) >> 4);
    if (e >= E) return;

    int src, dst;
    if (e64) {
        src = (int)edge_raw[2 * (size_t)e];
        dst = (int)edge_raw[2 * ((size_t)E + e)];
    } else {
        const int* e32 = (const int*)edge_raw;
        src = e32[e];
        dst = e32[(size_t)E + e];
    }

    const __bf16* hb = (const __bf16*)hm;
    const bf16x8 hs = *(const bf16x8*)(hb + (size_t)src * N_OUT + s * 8);
    const bf16x8 hd = *(const bf16x8*)(hb + (size_t)dst * N_OUT + s * 8);
    const f32x4 a0 = *(const f32x4*)(a + s * 8);
    const f32x4 a1 = *(const f32x4*)(a + s * 8 + 4);

    float sum = 0.f;
    #pragma unroll
    for (int i = 0; i < 4; ++i)
        sum += fabsf((float)hs[i] - (float)hd[i]) * a0[i];
    #pragma unroll
    for (int i = 0; i < 4; ++i)
        sum += fabsf((float)hs[4 + i] - (float)hd[4 + i]) * a1[i];

    sum += __shfl_xor(sum, 1, 64);
    sum += __shfl_xor(sum, 2, 64);
    sum += __shfl_xor(sum, 4, 64);
    sum += __shfl_xor(sum, 8, 64);

    if (s == 0) ew[e] = fmaxf(sum, 0.f);
}

__global__ __launch_bounds__(256) void edge_kernel_f32(
    const float* __restrict__ h,
    const uint32_t* __restrict__ edge_raw,
    const float* __restrict__ a,
    float* __restrict__ ew,
    int E)
{
    const int e64 = detect_i64(edge_raw);
    const int s = threadIdx.x & 15;
    const int e = (int)((blockIdx.x * 256 + threadIdx.x) >> 4);
    if (e >= E) return;

    int src, dst;
    if (e64) {
        src = (int)edge_raw[2 * (size_t)e];
        dst = (int)edge_raw[2 * ((size_t)E + e)];
    } else {
        const int* e32 = (const int*)edge_raw;
        src = e32[e];
        dst = e32[(size_t)E + e];
    }

    const f32x4 s0 = *(const f32x4*)(h + (size_t)src * N_OUT + s * 8);
    const f32x4 s1 = *(const f32x4*)(h + (size_t)src * N_OUT + s * 8 + 4);
    const f32x4 d0 = *(const f32x4*)(h + (size_t)dst * N_OUT + s * 8);
    const f32x4 d1 = *(const f32x4*)(h + (size_t)dst * N_OUT + s * 8 + 4);
    const f32x4 a0 = *(const f32x4*)(a + s * 8);
    const f32x4 a1 = *(const f32x4*)(a + s * 8 + 4);

    float sum = 0.f;
    #pragma unroll
    for (int i = 0; i < 4; ++i) sum += fabsf(s0[i] - d0[i]) * a0[i];
    #pragma unroll
    for (int i = 0; i < 4; ++i) sum += fabsf(s1[i] - d1[i]) * a1[i];

    sum += __shfl_xor(sum, 1, 64);
    sum += __shfl_xor(sum, 2, 64);
    sum += __shfl_xor(sum, 4, 64);
    sum += __shfl_xor(sum, 8, 64);

    if (s == 0) ew[e] = fmaxf(sum, 0.f);
}

extern "C" void kernel_launch(void* const* d_in, const int* in_sizes, int n_in,
                              void* d_out, int out_size, void* d_ws, size_t ws_size,
                              hipStream_t stream) {
    // d_in = { inputs fp32[100000,256], edge int64[2,E], weight fp32[256,128],
    //          a fp32[128,1] }  (dict order — validated R0-R7).
    // d_out = fp32: h[100000,128] then edge_weight[E].
    const float*    in   = (const float*)d_in[0];
    const uint32_t* edge = (const uint32_t*)d_in[1];
    const float*    w    = (const float*)d_in[2];
    const float*    a    = (const float*)d_in[3];

    float* h  = (float*)d_out;
    float* ew = h + (size_t)M_NODES * N_OUT;

    const size_t mirror_bytes = (size_t)M_NODES * N_OUT * sizeof(__hip_bfloat16);
    const size_t bt_off   = (mirror_bytes + 255) & ~(size_t)255;
    const size_t bt_bytes = (size_t)N_OUT * K_IN * sizeof(__hip_bfloat16); // 64 KB
    const int gblocks = (M_NODES + 63) / 64;
    const int eblocks = (N_EDGE * 16 + 255) / 256;

    if (ws_size >= bt_off + bt_bytes) {
        // expected path: mirror + Bt both in workspace
        __hip_bfloat16* hmir = (__hip_bfloat16*)d_ws;
        __hip_bfloat16* bt   = (__hip_bfloat16*)((char*)d_ws + bt_off);
        prep_bt<<<dim3(N_OUT), dim3(K_IN), 0, stream>>>(w, bt);
        gemm_h_mfma2<<<dim3(gblocks), dim3(256), 0, stream>>>(in, bt, h, hmir);
        edge_kernel_bf16<<<dim3(eblocks), dim3(256), 0, stream>>>(
            hmir, edge, a, ew, N_EDGE);
    } else if (ws_size >= bt_bytes) {
        __hip_bfloat16* bt = (__hip_bfloat16*)d_ws;
        prep_bt<<<dim3(N_OUT), dim3(K_IN), 0, stream>>>(w, bt);
        gemm_h_mfma2<<<dim3(gblocks), dim3(256), 0, stream>>>(in, bt, h, nullptr);
        edge_kernel_f32<<<dim3(eblocks), dim3(256), 0, stream>>>(
            h, edge, a, ew, N_EDGE);
    } else {
        gemm_h_mfma<<<dim3(gblocks), dim3(256), 0, stream>>>(in, w, h, nullptr);
        edge_kernel_f32<<<dim3(eblocks), dim3(256), 0, stream>>>(
            h, edge, a, ew, N_EDGE);
    }
}

// Round 9
// 330.461 us; speedup vs baseline: 1.0249x; 1.0249x over previous
//
#include <hip/hip_runtime.h>
#include <hip/hip_bf16.h>
#include <stdint.h>

typedef __bf16 bf16x8 __attribute__((ext_vector_type(8)));
typedef __bf16 bf16x4 __attribute__((ext_vector_type(4)));
typedef float  f32x4  __attribute__((ext_vector_type(4)));

#define M_NODES 100000
#define K_IN    256
#define N_OUT   128
#define N_EDGE  1600000

// ---------------------------------------------------------------------------
// Prep: Bt[n][k] = bf16( w[k][n] ) — 64 KB transposed weight table so GEMM
// B-fragments are single 16B loads (k contiguous per lane).
// ---------------------------------------------------------------------------
__global__ __launch_bounds__(256) void prep_bt(const float* __restrict__ w,
                                               __hip_bfloat16* __restrict__ bt) {
    const int col = blockIdx.x;              // 0..127
    const int k   = threadIdx.x;             // 0..255
    bt[(size_t)col * K_IN + k] = __float2bfloat16(w[(size_t)k * N_OUT + col]);
}

// ---------------------------------------------------------------------------
// Stage 1 v3: h[M,N] = in[M,K] @ w[K,N], MFMA 16x16x32 bf16, fp32 accum.
// Wave = 16 rows x 128 cols. K-loop identical to R8. NEW epilogue: acc ->
// per-wave LDS tile (8 KB, no barrier: intra-wave) -> row-major reload ->
// fully-coalesced plain stores (1 KB/instr fp32 h, 512 B/instr bf16 mirror).
// Nontemporal removed (nt + scattered 64B segments was the R7/R8 limiter).
// ---------------------------------------------------------------------------
__global__ __launch_bounds__(256) void gemm_h_mfma3(
    const float* __restrict__ in,            // [M,K] fp32
    const __hip_bfloat16* __restrict__ bt,   // [N,K] bf16 (transposed w)
    float* __restrict__ h,                   // [M,N] fp32 (d_out)
    __hip_bfloat16* __restrict__ hmir)       // [M,N] bf16 mirror (or null)
{
    __shared__ float cbuf[4][16 * N_OUT];    // 8 KB per wave

    const int lane = threadIdx.x & 63;
    const int wave = threadIdx.x >> 6;       // 0..3
    const int lr   = lane & 15;              // m (A) / n (B,C) within tile
    const int q    = lane >> 4;              // quad 0..3
    const int m0   = blockIdx.x * 64 + wave * 16;
    const int row  = m0 + lr;
    const __bf16* btb = (const __bf16*)bt;

    f32x4 acc[8];
    #pragma unroll
    for (int nt = 0; nt < 8; ++nt) acc[nt] = f32x4{0.f, 0.f, 0.f, 0.f};

    for (int kk = 0; kk < K_IN; kk += 32) {
        const int ka = kk + q * 8;           // lane's 8 contiguous k

        bf16x8 afrag;                        // A[m=lr][k=ka..ka+7]
        if (row < M_NODES) {
            const float* ap = in + (size_t)row * K_IN + ka;
            const f32x4 a0 = *(const f32x4*)ap;
            const f32x4 a1 = *(const f32x4*)(ap + 4);
            #pragma unroll
            for (int j = 0; j < 4; ++j) {
                afrag[j]     = (__bf16)a0[j];
                afrag[4 + j] = (__bf16)a1[j];
            }
        } else {
            #pragma unroll
            for (int j = 0; j < 8; ++j) afrag[j] = (__bf16)0.f;
        }

        bf16x8 bfrag[8];                     // B[k=ka+j][n=nt*16+lr] = Bt[n][k..]
        #pragma unroll
        for (int nt = 0; nt < 8; ++nt)
            bfrag[nt] = *(const bf16x8*)(btb + (size_t)(nt * 16 + lr) * K_IN + ka);

        #pragma unroll
        for (int nt = 0; nt < 8; ++nt)
            acc[nt] = __builtin_amdgcn_mfma_f32_16x16x32_bf16(
                afrag, bfrag[nt], acc[nt], 0, 0, 0);
    }

    // M_NODES % 16 == 0: a wave tile is either fully valid or fully OOB.
    if (m0 >= M_NODES) return;

    // --- epilogue: acc -> LDS (C/D layout), reload row-major, coalesce ---
    float* wbuf = cbuf[wave];
    #pragma unroll
    for (int nt = 0; nt < 8; ++nt)
        #pragma unroll
        for (int r = 0; r < 4; ++r)
            wbuf[(q * 4 + r) * N_OUT + nt * 16 + lr] = acc[nt][r];
    // intra-wave LDS RAW: compiler inserts lgkmcnt wait; no barrier needed.

    float* hrow = h + (size_t)m0 * N_OUT;
    __bf16* mrow = hmir ? (__bf16*)hmir + (size_t)m0 * N_OUT : nullptr;
    #pragma unroll
    for (int i = 0; i < 8; ++i) {
        const int idx = lane * 4 + i * 256;  // f32 index into the 16x128 tile
        const f32x4 v = *(const f32x4*)&wbuf[idx];
        *(f32x4*)(hrow + idx) = v;           // 1 KB contiguous per instruction
        if (mrow) {
            bf16x4 mv;
            #pragma unroll
            for (int j = 0; j < 4; ++j) mv[j] = (__bf16)v[j];
            *(bf16x4*)(mrow + idx) = mv;     // 512 B contiguous per instruction
        }
    }
}

// int64 edge indices < 1e5: every high word is 0. int32: odd words random.
__device__ inline int detect_i64(const uint32_t* p) {
    return __popcll(__ballot(p[2 * (threadIdx.x & 63) + 1] == 0u)) >= 60;
}

// ---------------------------------------------------------------------------
// Stage 2: edge_weight[e] = relu( sum_k |h[src][k] - h[dst][k]| * a[k] ).
// 16 lanes per edge; lane covers 8 contiguous channels (16B bf16 loads).
// ---------------------------------------------------------------------------
__global__ __launch_bounds__(256) void edge_kernel_bf16(
    const __hip_bfloat16* __restrict__ hm,
    const uint32_t* __restrict__ edge_raw,
    const float* __restrict__ a,
    float* __restrict__ ew,
    int E)
{
    const int e64 = detect_i64(edge_raw);
    const int s = threadIdx.x & 15;
    const int e = (int)((blockIdx.x * 256 + threadIdx.x) >> 4);
    if (e >= E) return;

    int src, dst;
    if (e64) {
        src = (int)edge_raw[2 * (size_t)e];
        dst = (int)edge_raw[2 * ((size_t)E + e)];
    } else {
        const int* e32 = (const int*)edge_raw;
        src = e32[e];
        dst = e32[(size_t)E + e];
    }

    const __bf16* hb = (const __bf16*)hm;
    const bf16x8 hs = *(const bf16x8*)(hb + (size_t)src * N_OUT + s * 8);
    const bf16x8 hd = *(const bf16x8*)(hb + (size_t)dst * N_OUT + s * 8);
    const f32x4 a0 = *(const f32x4*)(a + s * 8);
    const f32x4 a1 = *(const f32x4*)(a + s * 8 + 4);

    float sum = 0.f;
    #pragma unroll
    for (int i = 0; i < 4; ++i)
        sum += fabsf((float)hs[i] - (float)hd[i]) * a0[i];
    #pragma unroll
    for (int i = 0; i < 4; ++i)
        sum += fabsf((float)hs[4 + i] - (float)hd[4 + i]) * a1[i];

    sum += __shfl_xor(sum, 1, 64);
    sum += __shfl_xor(sum, 2, 64);
    sum += __shfl_xor(sum, 4, 64);
    sum += __shfl_xor(sum, 8, 64);

    if (s == 0) ew[e] = fmaxf(sum, 0.f);
}

__global__ __launch_bounds__(256) void edge_kernel_f32(
    const float* __restrict__ h,
    const uint32_t* __restrict__ edge_raw,
    const float* __restrict__ a,
    float* __restrict__ ew,
    int E)
{
    const int e64 = detect_i64(edge_raw);
    const int s = threadIdx.x & 15;
    const int e = (int)((blockIdx.x * 256 + threadIdx.x) >> 4);
    if (e >= E) return;

    int src, dst;
    if (e64) {
        src = (int)edge_raw[2 * (size_t)e];
        dst = (int)edge_raw[2 * ((size_t)E + e)];
    } else {
        const int* e32 = (const int*)edge_raw;
        src = e32[e];
        dst = e32[(size_t)E + e];
    }

    const f32x4 s0 = *(const f32x4*)(h + (size_t)src * N_OUT + s * 8);
    const f32x4 s1 = *(const f32x4*)(h + (size_t)src * N_OUT + s * 8 + 4);
    const f32x4 d0 = *(const f32x4*)(h + (size_t)dst * N_OUT + s * 8);
    const f32x4 d1 = *(const f32x4*)(h + (size_t)dst * N_OUT + s * 8 + 4);
    const f32x4 a0 = *(const f32x4*)(a + s * 8);
    const f32x4 a1 = *(const f32x4*)(a + s * 8 + 4);

    float sum = 0.f;
    #pragma unroll
    for (int i = 0; i < 4; ++i) sum += fabsf(s0[i] - d0[i]) * a0[i];
    #pragma unroll
    for (int i = 0; i < 4; ++i) sum += fabsf(s1[i] - d1[i]) * a1[i];

    sum += __shfl_xor(sum, 1, 64);
    sum += __shfl_xor(sum, 2, 64);
    sum += __shfl_xor(sum, 4, 64);
    sum += __shfl_xor(sum, 8, 64);

    if (s == 0) ew[e] = fmaxf(sum, 0.f);
}

extern "C" void kernel_launch(void* const* d_in, const int* in_sizes, int n_in,
                              void* d_out, int out_size, void* d_ws, size_t ws_size,
                              hipStream_t stream) {
    // d_in = { inputs fp32[100000,256], edge int64[2,E], weight fp32[256,128],
    //          a fp32[128,1] }  (dict order — validated R0-R8).
    // d_out = fp32: h[100000,128] then edge_weight[E].
    const float*    in   = (const float*)d_in[0];
    const uint32_t* edge = (const uint32_t*)d_in[1];
    const float*    w    = (const float*)d_in[2];
    const float*    a    = (const float*)d_in[3];

    float* h  = (float*)d_out;
    float* ew = h + (size_t)M_NODES * N_OUT;

    const size_t mirror_bytes = (size_t)M_NODES * N_OUT * sizeof(__hip_bfloat16);
    const size_t bt_off   = (mirror_bytes + 255) & ~(size_t)255;
    const size_t bt_bytes = (size_t)N_OUT * K_IN * sizeof(__hip_bfloat16); // 64 KB
    const int gblocks = (M_NODES + 63) / 64;
    const int eblocks = (N_EDGE * 16 + 255) / 256;

    if (ws_size >= bt_off + bt_bytes) {
        __hip_bfloat16* hmir = (__hip_bfloat16*)d_ws;
        __hip_bfloat16* bt   = (__hip_bfloat16*)((char*)d_ws + bt_off);
        prep_bt<<<dim3(N_OUT), dim3(K_IN), 0, stream>>>(w, bt);
        gemm_h_mfma3<<<dim3(gblocks), dim3(256), 0, stream>>>(in, bt, h, hmir);
        edge_kernel_bf16<<<dim3(eblocks), dim3(256), 0, stream>>>(
            hmir, edge, a, ew, N_EDGE);
    } else if (ws_size >= bt_bytes) {
        __hip_bfloat16* bt = (__hip_bfloat16*)d_ws;
        prep_bt<<<dim3(N_OUT), dim3(K_IN), 0, stream>>>(w, bt);
        gemm_h_mfma3<<<dim3(gblocks), dim3(256), 0, stream>>>(in, bt, h, nullptr);
        edge_kernel_f32<<<dim3(eblocks), dim3(256), 0, stream>>>(
            h, edge, a, ew, N_EDGE);
    } else {
        // minimal fallback: no workspace at all (not expected)
        prep_bt<<<dim3(N_OUT), dim3(K_IN), 0, stream>>>(w, (__hip_bfloat16*)d_out);
        gemm_h_mfma3<<<dim3(gblocks), dim3(256), 0, stream>>>(
            in, (__hip_bfloat16*)d_out, h, nullptr);
        edge_kernel_f32<<<dim3(eblocks), dim3(256), 0, stream>>>(
            h, edge, a, ew, N_EDGE);
    }
}